// Round 11
// baseline (62.941 us; speedup 1.0000x reference)
//
#include <hip/hip_runtime.h>
#include <hip/hip_bf16.h>
#include <math.h>

// Problem constants: B=4, Q=100, T=20, H=W=128 (HW=16384), C=80
#define B_ 4
#define Q_ 100
#define T_ 20
#define C_ 80
#define HW_ 16384

#define S_ 16                    // segments over HW
#define QG_ 10                   // queries per wave (register-tiled)
#define NQG_ (Q_ / QG_)          // 10 query-groups
#define TW_ 5                    // targets per wave (4 waves = 4 t-strips)
#define SEG4_ (HW_ / S_ / 4)     // 256 float4 per segment row
#define NIT_ (SEG4_ / 64)        // 4 iterations per wave

// Workspace layout (floats)
#define CELL_ 1640               // per (b,qg,seg): L[10][20][4] + I[10][20][4] + os[10][4]
#define NCELL_ (B_ * NQG_ * S_)  // 640
#define GS_OFF ((size_t)NCELL_ * CELL_)   // gsum: [b][seg][T_][4]

typedef float f32x4 __attribute__((ext_vector_type(4)));

// 4-stage reduce: lanes 0..3 hold disjoint 16-lane partials (their sum = wave sum).
__device__ __forceinline__ float wred4(float v) {
    v += __shfl_down(v, 32);
    v += __shfl_down(v, 16);
    v += __shfl_down(v, 8);
    v += __shfl_down(v, 4);
    return v;
}

template <bool WITH_G>
__device__ __forceinline__ void partial_body(const f32x4* __restrict__ o4,  // +seg+lane
                                             const f32x4* __restrict__ g4,  // +seg+lane
                                             float* __restrict__ rec,
                                             float* __restrict__ grec,
                                             int lane, int ts) {
    const int t0 = ts * TW_;

    float accL[QG_][TW_], accI[QG_][TW_], os[QG_], gs[TW_];
#pragma unroll
    for (int qi = 0; qi < QG_; ++qi) {
        os[qi] = 0.f;
#pragma unroll
        for (int tj = 0; tj < TW_; ++tj) { accL[qi][tj] = 0.f; accI[qi][tj] = 0.f; }
    }
#pragma unroll
    for (int tj = 0; tj < TW_; ++tj) gs[tj] = 0.f;

#pragma unroll
    for (int it = 0; it < NIT_; ++it) {
        const int ofs = it * 64;
        f32x4 o[QG_];
#pragma unroll
        for (int qi = 0; qi < QG_; ++qi) o[qi] = o4[(size_t)qi * (HW_ / 4) + ofs];
        f32x4 g[TW_];
#pragma unroll
        for (int tj = 0; tj < TW_; ++tj) g[tj] = g4[(size_t)(t0 + tj) * (HW_ / 4) + ofs];

        if (ts == 0) {   // wave-uniform branch: osum needed once per q
#pragma unroll
            for (int qi = 0; qi < QG_; ++qi)
                os[qi] += (o[qi].x + o[qi].y) + (o[qi].z + o[qi].w);
        }
        if (WITH_G) {
#pragma unroll
            for (int tj = 0; tj < TW_; ++tj)
                gs[tj] += (g[tj].x + g[tj].y) + (g[tj].z + g[tj].w);
        }
#pragma unroll
        for (int tj = 0; tj < TW_; ++tj) {
#pragma unroll
            for (int qi = 0; qi < QG_; ++qi) {
                accL[qi][tj] += (fabsf(o[qi].x - g[tj].x) + fabsf(o[qi].y - g[tj].y)) +
                                (fabsf(o[qi].z - g[tj].z) + fabsf(o[qi].w - g[tj].w));
                accI[qi][tj] = fmaf(o[qi].x, g[tj].x, accI[qi][tj]);
                accI[qi][tj] = fmaf(o[qi].y, g[tj].y, accI[qi][tj]);
                accI[qi][tj] = fmaf(o[qi].z, g[tj].z, accI[qi][tj]);
                accI[qi][tj] = fmaf(o[qi].w, g[tj].w, accI[qi][tj]);
            }
        }
    }

    // Epilogue: 4-stage reduces; lanes 0..3 write sub-partials.
#pragma unroll
    for (int qi = 0; qi < QG_; ++qi) {
#pragma unroll
        for (int tj = 0; tj < TW_; ++tj) {
            const float vL = wred4(accL[qi][tj]);
            const float vI = wred4(accI[qi][tj]);
            if (lane < 4) {
                rec[(qi * T_ + t0 + tj) * 4 + lane]       = vL;
                rec[800 + (qi * T_ + t0 + tj) * 4 + lane] = vI;
            }
        }
    }
    if (ts == 0) {
#pragma unroll
        for (int qi = 0; qi < QG_; ++qi) {
            const float vo = wred4(os[qi]);
            if (lane < 4) rec[1600 + qi * 4 + lane] = vo;
        }
    }
    if (WITH_G) {
#pragma unroll
        for (int tj = 0; tj < TW_; ++tj) {
            const float vg = wred4(gs[tj]);
            if (lane < 4) grec[(t0 + tj) * 4 + lane] = vg;
        }
    }
}

// Kernel 1: one wave per (b, q-group, t-strip, seg); 10x5 register tile.
__global__ __launch_bounds__(256) void partial_kernel(const float* __restrict__ outm,
                                                      const float* __restrict__ tgtm,
                                                      float* __restrict__ ws) {
    // XCD-batch partition: batch b on XCD pair {2b,2b+1}.
    const int r = blockIdx.x & 7;
    const int m = blockIdx.x >> 3;
    const int b = r >> 1;
    const int l = m * 2 + (r & 1);        // [0,160): qg(10) x seg(16)
    const int qg = l >> 4;
    const int seg = l & (S_ - 1);

    const int lane = threadIdx.x & 63;
    const int ts   = threadIdx.x >> 6;    // t-strip = wave id

    const f32x4* o4 = (const f32x4*)(outm + ((size_t)b * Q_ + qg * QG_) * HW_) + seg * SEG4_ + lane;
    const f32x4* g4 = (const f32x4*)(tgtm + (size_t)b * T_ * HW_) + seg * SEG4_ + lane;
    float* rec  = ws + ((size_t)(b * NQG_ + qg) * S_ + seg) * CELL_;
    float* grec = ws + GS_OFF + (size_t)(b * S_ + seg) * T_ * 4;

    if (qg == 0) partial_body<true>(o4, g4, rec, grec, lane, ts);
    else         partial_body<false>(o4, g4, rec, grec, lane, ts);
}

// Kernel 2: reduce segments/sub-partials + epilogue (softmax class cost + dice).
__global__ __launch_bounds__(64) void finalize_kernel(const float* __restrict__ probs,
                                                      const int*   __restrict__ labels,
                                                      const float* __restrict__ ws,
                                                      float* __restrict__ out) {
    const int bq = blockIdx.x;
    const int b = bq / Q_;
    const int q = bq % Q_;
    const int qg = q / QG_;
    const int qi = q % QG_;

    __shared__ float s_logit[C_];
    for (int c = threadIdx.x; c < C_; c += 64)
        s_logit[c] = probs[(size_t)bq * C_ + c];
    __syncthreads();

    const int t = threadIdx.x;
    if (t < T_) {
        float L = 0.f, I = 0.f, osum = 0.f, tsum = 0.f;
#pragma unroll
        for (int seg = 0; seg < S_; ++seg) {
            const float4* r4 = (const float4*)(ws + ((size_t)(b * NQG_ + qg) * S_ + seg) * CELL_);
            const float4* d4 = (const float4*)(ws + GS_OFF + (size_t)(b * S_ + seg) * T_ * 4);
            const float4 a = r4[qi * T_ + t];
            const float4 v = r4[200 + qi * T_ + t];
            const float4 c = r4[400 + qi];
            const float4 d = d4[t];
            L    += (a.x + a.y) + (a.z + a.w);
            I    += (v.x + v.y) + (v.z + v.w);
            osum += (c.x + c.y) + (c.z + c.w);
            tsum += (d.x + d.y) + (d.z + d.w);
        }
        float mx = -INFINITY;
#pragma unroll
        for (int c = 0; c < C_; ++c) mx = fmaxf(mx, s_logit[c]);
        float sum = 0.f;
#pragma unroll
        for (int c = 0; c < C_; ++c) sum += __expf(s_logit[c] - mx);
        const int lab = labels[b * T_ + t];
        const float p = __expf(s_logit[lab] - mx) / sum;

        const float denom = osum + tsum;
        const float dice = 1.f - (2.f * I + 1.f) / (denom + 1.f);

        out[(size_t)bq * T_ + t] = L - p + dice;
    }
}

extern "C" void kernel_launch(void* const* d_in, const int* in_sizes, int n_in,
                              void* d_out, int out_size, void* d_ws, size_t ws_size,
                              hipStream_t stream) {
    const float* out_probs     = (const float*)d_in[0]; // [B,Q,C]
    const float* out_masks     = (const float*)d_in[1]; // [B,Q,H,W]
    const float* target_masks  = (const float*)d_in[2]; // [B,T,H,W]
    const int*   target_labels = (const int*)d_in[3];   // [B,T]
    float* out = (float*)d_out;                         // [B,Q,T]

    float* partials = (float*)d_ws;                     // ~4.2 MB

    partial_kernel<<<B_ * NQG_ * S_, 256, 0, stream>>>(out_masks, target_masks, partials);
    finalize_kernel<<<B_ * Q_, 64, 0, stream>>>(out_probs, target_labels, partials, out);
}

// Round 12
// 39.188 us; speedup vs baseline: 1.6061x; 1.6061x over previous
//
#include <hip/hip_runtime.h>
#include <hip/hip_bf16.h>
#include <math.h>

// Problem constants: B=4, Q=100, T=20, H=W=128 (HW=16384), C=80
#define B_ 4
#define Q_ 100
#define T_ 20
#define C_ 80
#define HW_ 16384

#define S_ 16                     // segments over HW
#define SLICE4_ (HW_ / S_ / 4)    // 256 float4 per row-slice
#define NIT_ (SLICE4_ / 64)       // 4 compute iterations
#define QB_ 5                     // q-blocks of 20 queries
#define TQ_ 4                     // t-quarters of 5 targets
#define TW_ 5                     // targets per block (all waves share)
#define QW_ 5                     // queries per wave
#define NWG_ (B_ * QB_ * TQ_ * S_)  // 1280 blocks

// Workspace float offsets: per (b,q,t): 16 seg * 4 sub-partials
#define WL_OFF 0                         // [B*Q][T][16][4] = 512000
#define WI_OFF 512000                    // same size
#define OS_OFF 1024000                   // [B*Q][16][4] = 25600
#define GS_OFF 1049600                   // [B*T][16][4] = 5120

typedef float f32x4 __attribute__((ext_vector_type(4)));

// Async global->LDS, 16B/lane; dest = wave-uniform base + lane*16 (satisfied).
__device__ __forceinline__ void stage16(const f32x4* gsrc, f32x4* ldst) {
    __builtin_amdgcn_global_load_lds(
        (const __attribute__((address_space(1))) void*)gsrc,
        (__attribute__((address_space(3))) void*)ldst,
        16, 0, 0);
}

// 4-stage reduce: lanes 0..3 hold disjoint 16-lane partials (sum = wave sum).
__device__ __forceinline__ float wred4(float v) {
    v += __shfl_down(v, 32);
    v += __shfl_down(v, 16);
    v += __shfl_down(v, 8);
    v += __shfl_down(v, 4);
    return v;
}

// Kernel 1: block = (b, 20-q group, 5-t quarter, seg). g rows staged to LDS ONCE;
// then 4 barrier-free iterations: 5 o global loads + 5 LDS g reads + 25-cell tile.
__global__ __launch_bounds__(256) void partial_kernel(const float* __restrict__ outm,
                                                      const float* __restrict__ tgtm,
                                                      float* __restrict__ ws) {
    __shared__ f32x4 glds[TW_ * SLICE4_];   // 5 rows x 4KB = 20 KB

    // Bijective XCD-chunked swizzle (1280 % 8 == 0, chunk = 160).
    const int wgid = (blockIdx.x & 7) * (NWG_ / 8) + (blockIdx.x >> 3);
    const int b  = wgid / (QB_ * TQ_ * S_);
    int rem      = wgid % (QB_ * TQ_ * S_);
    const int qb = rem / (TQ_ * S_);
    rem          = rem % (TQ_ * S_);
    const int tq = rem / S_;
    const int seg = rem % S_;

    const int tid  = threadIdx.x;
    const int lane = tid & 63;
    const int wave = tid >> 6;
    const int t0    = tq * TW_;
    const int qbase = qb * 20 + wave * QW_;

    const f32x4* o4 = (const f32x4*)(outm + ((size_t)b * Q_ + qbase) * HW_) + seg * SLICE4_ + lane;
    const f32x4* g4 = (const f32x4*)(tgtm + ((size_t)b * T_ + t0) * HW_) + seg * SLICE4_;

    // Stage the 5 shared g rows (each row: 256 f4 covered by the 256 threads).
#pragma unroll
    for (int k = 0; k < TW_; ++k)
        stage16(g4 + (size_t)k * (HW_ / 4) + tid, &glds[k * SLICE4_ + tid]);

    float accL[QW_][TW_], accI[QW_][TW_], os[QW_], gs[TW_];
#pragma unroll
    for (int qi = 0; qi < QW_; ++qi) {
        os[qi] = 0.f;
#pragma unroll
        for (int tj = 0; tj < TW_; ++tj) { accL[qi][tj] = 0.f; accI[qi][tj] = 0.f; }
    }
#pragma unroll
    for (int tj = 0; tj < TW_; ++tj) gs[tj] = 0.f;

    __syncthreads();   // drains the async stage; the ONLY barrier

#pragma unroll
    for (int it = 0; it < NIT_; ++it) {
        const int ofs = it * 64;
        f32x4 o[QW_];
#pragma unroll
        for (int qi = 0; qi < QW_; ++qi) o[qi] = o4[(size_t)qi * (HW_ / 4) + ofs];
        f32x4 g[TW_];
#pragma unroll
        for (int tj = 0; tj < TW_; ++tj) g[tj] = glds[tj * SLICE4_ + ofs + lane];

        if (tq == 0) {            // block-uniform: osum needed once per q
#pragma unroll
            for (int qi = 0; qi < QW_; ++qi)
                os[qi] += (o[qi].x + o[qi].y) + (o[qi].z + o[qi].w);
        }
        if (qb == 0 && wave == 0) {  // wave-uniform: gsum once per (b,t,seg)
#pragma unroll
            for (int tj = 0; tj < TW_; ++tj)
                gs[tj] += (g[tj].x + g[tj].y) + (g[tj].z + g[tj].w);
        }
#pragma unroll
        for (int tj = 0; tj < TW_; ++tj) {
#pragma unroll
            for (int qi = 0; qi < QW_; ++qi) {
                accL[qi][tj] += (fabsf(o[qi].x - g[tj].x) + fabsf(o[qi].y - g[tj].y)) +
                                (fabsf(o[qi].z - g[tj].z) + fabsf(o[qi].w - g[tj].w));
                accI[qi][tj] = fmaf(o[qi].x, g[tj].x, accI[qi][tj]);
                accI[qi][tj] = fmaf(o[qi].y, g[tj].y, accI[qi][tj]);
                accI[qi][tj] = fmaf(o[qi].z, g[tj].z, accI[qi][tj]);
                accI[qi][tj] = fmaf(o[qi].w, g[tj].w, accI[qi][tj]);
            }
        }
    }

    // Epilogue: 4-stage reduces; lanes 0..3 write sub-partials.
    float* WL = ws + WL_OFF;
    float* WI = ws + WI_OFF;
    float* OS = ws + OS_OFF;
    float* GS = ws + GS_OFF;
#pragma unroll
    for (int qi = 0; qi < QW_; ++qi) {
#pragma unroll
        for (int tj = 0; tj < TW_; ++tj) {
            const float vL = wred4(accL[qi][tj]);
            const float vI = wred4(accI[qi][tj]);
            if (lane < 4) {
                const size_t idx = (((size_t)(b * Q_ + qbase + qi) * T_) + t0 + tj) * 64 + seg * 4 + lane;
                WL[idx] = vL;
                WI[idx] = vI;
            }
        }
        if (tq == 0) {
            const float vo = wred4(os[qi]);
            if (lane < 4) OS[(size_t)(b * Q_ + qbase + qi) * 64 + seg * 4 + lane] = vo;
        }
    }
    if (qb == 0 && wave == 0) {
#pragma unroll
        for (int tj = 0; tj < TW_; ++tj) {
            const float vg = wred4(gs[tj]);
            if (lane < 4) GS[(size_t)(b * T_ + t0 + tj) * 64 + seg * 4 + lane] = vg;
        }
    }
}

// Kernel 2: reduce seg/sub-partials + epilogue (softmax class cost + dice).
__global__ __launch_bounds__(64) void finalize_kernel(const float* __restrict__ probs,
                                                      const int*   __restrict__ labels,
                                                      const float* __restrict__ ws,
                                                      float* __restrict__ out) {
    const int bq = blockIdx.x;
    const int b = bq / Q_;

    __shared__ float s_logit[C_];
    for (int c = threadIdx.x; c < C_; c += 64)
        s_logit[c] = probs[(size_t)bq * C_ + c];
    __syncthreads();

    const int t = threadIdx.x;
    if (t < T_) {
        const float4* WL4 = (const float4*)(ws + WL_OFF) + ((size_t)bq * T_ + t) * 16;
        const float4* WI4 = (const float4*)(ws + WI_OFF) + ((size_t)bq * T_ + t) * 16;
        const float4* OS4 = (const float4*)(ws + OS_OFF) + (size_t)bq * 16;
        const float4* GS4 = (const float4*)(ws + GS_OFF) + ((size_t)b * T_ + t) * 16;
        float L = 0.f, I = 0.f, osum = 0.f, tsum = 0.f;
#pragma unroll
        for (int s = 0; s < S_; ++s) {
            const float4 a = WL4[s];
            const float4 v = WI4[s];
            const float4 c = OS4[s];
            const float4 d = GS4[s];
            L    += (a.x + a.y) + (a.z + a.w);
            I    += (v.x + v.y) + (v.z + v.w);
            osum += (c.x + c.y) + (c.z + c.w);
            tsum += (d.x + d.y) + (d.z + d.w);
        }
        float mx = -INFINITY;
#pragma unroll
        for (int c = 0; c < C_; ++c) mx = fmaxf(mx, s_logit[c]);
        float sum = 0.f;
#pragma unroll
        for (int c = 0; c < C_; ++c) sum += __expf(s_logit[c] - mx);
        const int lab = labels[(size_t)b * T_ + t];
        const float p = __expf(s_logit[lab] - mx) / sum;

        const float denom = osum + tsum;
        const float dice = 1.f - (2.f * I + 1.f) / (denom + 1.f);

        out[(size_t)bq * T_ + t] = L - p + dice;
    }
}

extern "C" void kernel_launch(void* const* d_in, const int* in_sizes, int n_in,
                              void* d_out, int out_size, void* d_ws, size_t ws_size,
                              hipStream_t stream) {
    const float* out_probs     = (const float*)d_in[0]; // [B,Q,C]
    const float* out_masks     = (const float*)d_in[1]; // [B,Q,H,W]
    const float* target_masks  = (const float*)d_in[2]; // [B,T,H,W]
    const int*   target_labels = (const int*)d_in[3];   // [B,T]
    float* out = (float*)d_out;                         // [B,Q,T]

    float* partials = (float*)d_ws;                     // ~4.2 MB

    partial_kernel<<<NWG_, 256, 0, stream>>>(out_masks, target_masks, partials);
    finalize_kernel<<<B_ * Q_, 64, 0, stream>>>(out_probs, target_labels, partials, out);
}

// Round 13
// 34.589 us; speedup vs baseline: 1.8197x; 1.1330x over previous
//
#include <hip/hip_runtime.h>
#include <hip/hip_bf16.h>
#include <math.h>

// Problem constants: B=4, Q=100, T=20, H=W=128 (HW=16384), C=80
#define B_ 4
#define Q_ 100
#define T_ 20
#define C_ 80
#define HW_ 16384
#define HW4_ (HW_ / 4)

#define S_ 8                     // segments over HW
#define QP_ (Q_ / 2)             // 50 query-pairs
#define SEG4_ (HW_ / S_ / 4)     // 512 float4 per segment
#define NIT_ (SEG4_ / 64)        // 8 iterations per wave
#define TW_ 5                    // t's per wave (4 waves = 4 t-strips)

// Workspace float offsets (sub-partial layout: [..][S_][4])
#define WL_OFF 0                                   // [B*Q][T][S_][4] = 256000
#define WI_OFF (B_ * Q_ * T_ * S_ * 4)             // 256000
#define OS_OFF (2 * B_ * Q_ * T_ * S_ * 4)         // 512000: [B*Q][S_][4]
#define GS_OFF (OS_OFF + B_ * Q_ * S_ * 4)         // [B*T][S_][4]

typedef float f32x4 __attribute__((ext_vector_type(4)));

// 4-stage reduce: lanes 0..3 hold disjoint 16-lane partials (sum = wave sum).
__device__ __forceinline__ float wred4(float v) {
    v += __shfl_down(v, 32);
    v += __shfl_down(v, 16);
    v += __shfl_down(v, 8);
    v += __shfl_down(v, 4);
    return v;
}

// One independent wave per (b, qpair, tstrip, seg). No LDS, no barriers.
// Explicit 2-deep register double-buffer: issue iter i+1's 7 loads before
// computing iter i, so the vmcnt wait overlaps ~250 cyc of VALU.
template <bool WITH_G>
__device__ __forceinline__ void partial_body(const f32x4* __restrict__ o4,  // +seg+lane
                                             const f32x4* __restrict__ g4,  // +seg+lane
                                             float* __restrict__ ws,
                                             int blin, int b, int seg,
                                             int lane, int ts) {
    const int t0 = ts * TW_;

    float accL[2][TW_], accI[2][TW_], os[2], gs[TW_];
#pragma unroll
    for (int qi = 0; qi < 2; ++qi) {
        os[qi] = 0.f;
#pragma unroll
        for (int tj = 0; tj < TW_; ++tj) { accL[qi][tj] = 0.f; accI[qi][tj] = 0.f; }
    }
#pragma unroll
    for (int tj = 0; tj < TW_; ++tj) gs[tj] = 0.f;

    f32x4 oc[2], gc[TW_], on[2], gn[TW_];
    // Preload iteration 0.
#pragma unroll
    for (int qi = 0; qi < 2; ++qi) oc[qi] = o4[(size_t)qi * HW4_];
#pragma unroll
    for (int tj = 0; tj < TW_; ++tj) gc[tj] = g4[(size_t)(t0 + tj) * HW4_];

#pragma unroll
    for (int it = 0; it < NIT_; ++it) {
        if (it + 1 < NIT_) {
            const int ofs = (it + 1) * 64;
#pragma unroll
            for (int qi = 0; qi < 2; ++qi) on[qi] = o4[(size_t)qi * HW4_ + ofs];
#pragma unroll
            for (int tj = 0; tj < TW_; ++tj) gn[tj] = g4[(size_t)(t0 + tj) * HW4_ + ofs];
        }
        if (ts == 0) {   // wave-uniform: osum computed by one t-strip only
#pragma unroll
            for (int qi = 0; qi < 2; ++qi)
                os[qi] += (oc[qi].x + oc[qi].y) + (oc[qi].z + oc[qi].w);
        }
        if (WITH_G) {
#pragma unroll
            for (int tj = 0; tj < TW_; ++tj)
                gs[tj] += (gc[tj].x + gc[tj].y) + (gc[tj].z + gc[tj].w);
        }
#pragma unroll
        for (int tj = 0; tj < TW_; ++tj) {
            const f32x4 g = gc[tj];
#pragma unroll
            for (int qi = 0; qi < 2; ++qi) {
                const f32x4 o = oc[qi];
                accL[qi][tj] += (fabsf(o.x - g.x) + fabsf(o.y - g.y)) +
                                (fabsf(o.z - g.z) + fabsf(o.w - g.w));
                accI[qi][tj] = fmaf(o.x, g.x, accI[qi][tj]);
                accI[qi][tj] = fmaf(o.y, g.y, accI[qi][tj]);
                accI[qi][tj] = fmaf(o.z, g.z, accI[qi][tj]);
                accI[qi][tj] = fmaf(o.w, g.w, accI[qi][tj]);
            }
        }
        if (it + 1 < NIT_) {
#pragma unroll
            for (int qi = 0; qi < 2; ++qi) oc[qi] = on[qi];
#pragma unroll
            for (int tj = 0; tj < TW_; ++tj) gc[tj] = gn[tj];
        }
    }

    // Epilogue: 4-stage reduces; lanes 0..3 write sub-partials.
    float* WL = ws + WL_OFF;
    float* WI = ws + WI_OFF;
    float* OS = ws + OS_OFF;
    float* GS = ws + GS_OFF;
#pragma unroll
    for (int qi = 0; qi < 2; ++qi) {
#pragma unroll
        for (int tj = 0; tj < TW_; ++tj) {
            const float vL = wred4(accL[qi][tj]);
            const float vI = wred4(accI[qi][tj]);
            if (lane < 4) {
                const size_t idx = ((size_t)(blin / S_ * 2 + qi) * T_ + t0 + tj) * (S_ * 4)
                                   + seg * 4 + lane;
                WL[idx] = vL;
                WI[idx] = vI;
            }
        }
        if (ts == 0) {
            const float vo = wred4(os[qi]);
            if (lane < 4) OS[(size_t)(blin / S_ * 2 + qi) * (S_ * 4) + seg * 4 + lane] = vo;
        }
    }
    if (WITH_G) {
#pragma unroll
        for (int tj = 0; tj < TW_; ++tj) {
            const float vg = wred4(gs[tj]);
            if (lane < 4) GS[(size_t)(b * T_ + t0 + tj) * (S_ * 4) + seg * 4 + lane] = vg;
        }
    }
}

__global__ __launch_bounds__(256) void partial_kernel(const float* __restrict__ outm,
                                                      const float* __restrict__ tgtm,
                                                      float* __restrict__ ws) {
    // XCD-batch partition: batch b on XCD pair {2b,2b+1}.
    const int r = blockIdx.x & 7;
    const int m = blockIdx.x >> 3;
    const int b = r >> 1;
    const int l = m * 2 + (r & 1);   // [0,400): qp(50) x seg(8)
    const int qp = l >> 3;
    const int seg = l & (S_ - 1);
    const int blin = (b * QP_ + qp) * S_ + seg;   // (blin/S_)*2 == global qpair base

    const int lane = threadIdx.x & 63;
    const int ts   = threadIdx.x >> 6;   // t-strip = wave id

    const f32x4* o4 = (const f32x4*)(outm + ((size_t)b * Q_ + qp * 2) * HW_) + seg * SEG4_ + lane;
    const f32x4* g4 = (const f32x4*)(tgtm + (size_t)b * T_ * HW_) + seg * SEG4_ + lane;

    if (qp == 0) partial_body<true>(o4, g4, ws, blin, b, seg, lane, ts);
    else         partial_body<false>(o4, g4, ws, blin, b, seg, lane, ts);
}

// Kernel 2: reduce seg/sub-partials + epilogue (softmax class cost + dice).
__global__ __launch_bounds__(64) void finalize_kernel(const float* __restrict__ probs,
                                                      const int*   __restrict__ labels,
                                                      const float* __restrict__ ws,
                                                      float* __restrict__ out) {
    const int bq = blockIdx.x;
    const int b = bq / Q_;

    __shared__ float s_logit[C_];
    for (int c = threadIdx.x; c < C_; c += 64)
        s_logit[c] = probs[(size_t)bq * C_ + c];
    __syncthreads();

    const int t = threadIdx.x;
    if (t < T_) {
        const float4* WL4 = (const float4*)(ws + WL_OFF) + ((size_t)bq * T_ + t) * S_;
        const float4* WI4 = (const float4*)(ws + WI_OFF) + ((size_t)bq * T_ + t) * S_;
        const float4* OS4 = (const float4*)(ws + OS_OFF) + (size_t)bq * S_;
        const float4* GS4 = (const float4*)(ws + GS_OFF) + ((size_t)b * T_ + t) * S_;
        float L = 0.f, I = 0.f, osum = 0.f, tsum = 0.f;
#pragma unroll
        for (int s = 0; s < S_; ++s) {
            const float4 a = WL4[s];
            const float4 v = WI4[s];
            const float4 c = OS4[s];
            const float4 d = GS4[s];
            L    += (a.x + a.y) + (a.z + a.w);
            I    += (v.x + v.y) + (v.z + v.w);
            osum += (c.x + c.y) + (c.z + c.w);
            tsum += (d.x + d.y) + (d.z + d.w);
        }
        float mx = -INFINITY;
#pragma unroll
        for (int c = 0; c < C_; ++c) mx = fmaxf(mx, s_logit[c]);
        float sum = 0.f;
#pragma unroll
        for (int c = 0; c < C_; ++c) sum += __expf(s_logit[c] - mx);
        const int lab = labels[(size_t)b * T_ + t];
        const float p = __expf(s_logit[lab] - mx) / sum;

        const float denom = osum + tsum;
        const float dice = 1.f - (2.f * I + 1.f) / (denom + 1.f);

        out[(size_t)bq * T_ + t] = L - p + dice;
    }
}

extern "C" void kernel_launch(void* const* d_in, const int* in_sizes, int n_in,
                              void* d_out, int out_size, void* d_ws, size_t ws_size,
                              hipStream_t stream) {
    const float* out_probs     = (const float*)d_in[0]; // [B,Q,C]
    const float* out_masks     = (const float*)d_in[1]; // [B,Q,H,W]
    const float* target_masks  = (const float*)d_in[2]; // [B,T,H,W]
    const int*   target_labels = (const int*)d_in[3];   // [B,T]
    float* out = (float*)d_out;                         // [B,Q,T]

    float* partials = (float*)d_ws;                     // ~2.1 MB

    partial_kernel<<<B_ * QP_ * S_, 256, 0, stream>>>(out_masks, target_masks, partials);
    finalize_kernel<<<B_ * Q_, 64, 0, stream>>>(out_probs, target_labels, partials, out);
}